// Round 8
// baseline (134.801 us; speedup 1.0000x reference)
//
#include <hip/hip_runtime.h>
#include <hip/hip_bf16.h>

#define SIZE 4096
#define BM 256
#define BK 64
#define NT (SIZE / BK)     // 64 K-tiles
#define NBG (SIZE / BM)    // 16x16 grid of 256^2 tiles

typedef __bf16 bf16x8 __attribute__((ext_vector_type(8)));
typedef __bf16 bf16x4 __attribute__((ext_vector_type(4)));
typedef float f32x4 __attribute__((ext_vector_type(4)));
typedef float f32x16 __attribute__((ext_vector_type(16)));

__device__ __forceinline__ void gload_lds16(const void* gsrc, void* ldst) {
  __builtin_amdgcn_global_load_lds(
      (const __attribute__((address_space(1))) unsigned int*)gsrc,
      (__attribute__((address_space(3))) unsigned int*)ldst, 16, 0, 0);
}

// ---------------------------------------------------------------------------
// Kernel 1: build L (bf16). One 256-thread block per row. 4 cols/thread.
// fp32 throughout (matches reference underflow).
// ---------------------------------------------------------------------------
__global__ __launch_bounds__(256) void build_L(const float* __restrict__ p,
                                               __bf16* __restrict__ Lb) {
  const int row = blockIdx.x;
  const int tid = threadIdx.x;
  const int lane = tid & 63;
  const int wid = tid >> 6;
  const long base = (long)row * (row - 1) / 2;

  __shared__ float wtot[4];
  float carry = 1.0f;

  for (int j0 = 0; j0 < SIZE; j0 += 1024) {
    const int jb = j0 + tid * 4;
    if (j0 > row) {
      bf16x4 z = {(__bf16)0.0f, (__bf16)0.0f, (__bf16)0.0f, (__bf16)0.0f};
      *(bf16x4*)&Lb[(size_t)row * SIZE + jb] = z;
      continue;
    }
    float t[4], v[4];
#pragma unroll
    for (int e = 0; e < 4; ++e) {
      const int j = jb + e;
      if (j < row) {
        const float th = tanhf(p[base + j]);
        t[e] = th;
        v[e] = 1.0f - th * th;
      } else {
        t[e] = (j == row) ? 1.0f : 0.0f;
        v[e] = 1.0f;
      }
    }
    const float vt = v[0] * v[1] * v[2] * v[3];
    float incl = vt;
#pragma unroll
    for (int off = 1; off < 64; off <<= 1) {
      float o = __shfl_up(incl, off, 64);
      if (lane >= off) incl *= o;
    }
    if (lane == 63) wtot[wid] = incl;
    __syncthreads();
    float pre = carry;
    for (int w = 0; w < wid; ++w) pre *= wtot[w];
    float excl = __shfl_up(incl, 1, 64);
    if (lane == 0) excl = 1.0f;
    float s = pre * excl;
    bf16x4 out;
#pragma unroll
    for (int e = 0; e < 4; ++e) {
      out[e] = (__bf16)(t[e] * sqrtf(s));
      s *= v[e];
    }
    *(bf16x4*)&Lb[(size_t)row * SIZE + jb] = out;
    const float tot = wtot[0] * wtot[1] * wtot[2] * wtot[3];
    __syncthreads();
    carry *= tot;
  }
}

// ---------------------------------------------------------------------------
// Kernel 2: C = L*L^T, 256x256, BK=64, 8 waves, 32x32x16 MFMA, chunk-XOR
// swizzle (R7: 0 conflicts). NEW vs R7: cross-phase read pipelining.
// Each phase issues the NEXT phase's 8 ds_read_b128, then waits lgkmcnt(8)
// (current operands confirmed; next 8 drain under the MFMA cluster).
// Phase i body: {stage; [i3: vmcnt gate + barrier]; reads(i+1); lgkm(8);
//               MFMA(i); barrier}.  5 barriers/tile (was 8).
// Stage-safety map (region <- last reads issued / confirmed):
//   i0 stages nbuf A-kh1 : last reads @i2 prev tile, confirmed b2@i3   SAFE
//   i1 stages buf  B-kh0 : last reads @i0 (ph1 set), >=150cy + L2-path SAFE
//   i2 stages buf  A-kh0 : last reads @i0, confirmed by b2@i1          SAFE
//   i3 stages buf  B-kh1 : last reads @i2, one full phase margin       SAFE
// Tile-boundary (nbuf) reads strictly after vmcnt(6)+barrier. Final phase
// (t=NT-1,i3) issues no reads -> lgkmcnt(0) peel.
// ---------------------------------------------------------------------------
__global__ __launch_bounds__(512, 1) void syrk8(const __bf16* __restrict__ Lb,
                                                float* __restrict__ C) {
  __shared__ __bf16 lds[2][2][2][256][32];  // [buf][ab][kh][row][k] 128 KiB

  const int bid0 = blockIdx.x;
  const int bid = (bid0 & 7) * 32 + (bid0 >> 3);  // bijective XCD chunking
  const int bi = bid >> 4, bj = bid & 15;

  const int tid = threadIdx.x;
  const int lane = tid & 63;
  const int wid = tid >> 6;
  const int wm = wid >> 2;
  const int wn = wid & 3;
  const int r32 = lane & 31;
  const int khi = lane >> 5;
  const int swzf = ((r32 >> 1) & 3) ^ ((lane >> 4) & 1);
  const int ck0 = ((0 | khi) ^ swzf) * 8;
  const int ck1 = ((2 | khi) ^ swzf) * 8;

  const size_t rowA0 = (size_t)bi * 256;
  const size_t rowB0 = (size_t)bj * 256;

  const int srow = wid * 32 + (lane >> 2);
  const int sch = (lane & 3) ^ ((lane >> 3) & 3);
  const int soff0 = sch * 8;
  const int soff1 = (sch ^ 1) * 8;

  const __bf16* g0 = Lb + (rowA0 + srow) * SIZE;       // A kh0 stream
  const __bf16* g1 = Lb + (rowB0 + srow) * SIZE;       // B kh0
  const __bf16* g2 = Lb + (rowA0 + srow) * SIZE + 32;  // A kh1
  const __bf16* g3 = Lb + (rowB0 + srow) * SIZE + 32;  // B kh1

  auto stg = [&](const __bf16*& gp, int ab, int kh, int dstbuf) {
    __bf16* base = &lds[dstbuf][ab][kh][0][0];
    gload_lds16(gp + soff0, base + (wid * 32) * 32);
    gload_lds16(gp + (size_t)16 * SIZE + soff1, base + (wid * 32 + 16) * 32);
    gp += BK;
  };

  f32x16 acc[4][2] = {};
  bf16x8 afA[2][2], bfA[2][2], afB[2][2], bfB[2][2];

// 8 ds_read_b128: full (kh, mh) operand set into one register group
#define LDRD(AF, BF, BSEL, KH, MH)                                         \
  {                                                                        \
    _Pragma("unroll") for (int mb = 0; mb < 2; ++mb) {                     \
      const __bf16* ap =                                                   \
          &lds[BSEL][0][KH][wm * 128 + ((MH)*2 + mb) * 32 + r32][0];       \
      AF[mb][0] = *(const bf16x8*)(ap + ck0);                              \
      AF[mb][1] = *(const bf16x8*)(ap + ck1);                              \
    }                                                                      \
    _Pragma("unroll") for (int nb = 0; nb < 2; ++nb) {                     \
      const __bf16* bp = &lds[BSEL][1][KH][wn * 64 + nb * 32 + r32][0];    \
      BF[nb][0] = *(const bf16x8*)(bp + ck0);                              \
      BF[nb][1] = *(const bf16x8*)(bp + ck1);                              \
    }                                                                      \
  }

#define MMA(AF, BF, MH)                                                    \
  {                                                                        \
    __builtin_amdgcn_s_setprio(1);                                         \
    _Pragma("unroll") for (int mb = 0; mb < 2; ++mb)                       \
        _Pragma("unroll") for (int nb = 0; nb < 2; ++nb)                   \
            _Pragma("unroll") for (int ks = 0; ks < 2; ++ks)               \
                acc[(MH)*2 + mb][nb] =                                     \
        __builtin_amdgcn_mfma_f32_32x32x16_bf16(AF[mb][ks], BF[nb][ks],    \
                                                acc[(MH)*2 + mb][nb], 0,   \
                                                0, 0);                     \
    __builtin_amdgcn_s_setprio(0);                                         \
  }

#define LGKM8 asm volatile("s_waitcnt lgkmcnt(8)" ::: "memory");           \
  __builtin_amdgcn_sched_barrier(0)
#define LGKM0 asm volatile("s_waitcnt lgkmcnt(0)" ::: "memory");           \
  __builtin_amdgcn_sched_barrier(0)

  // prologue: t0 all 4 halves, then t1's {B-kh0, A-kh0, B-kh1}
  stg(g0, 0, 0, 0); stg(g1, 1, 0, 0); stg(g2, 0, 1, 0); stg(g3, 1, 1, 0);
  stg(g1, 1, 0, 1); stg(g0, 0, 0, 1); stg(g3, 1, 1, 1);
  asm volatile("s_waitcnt vmcnt(6)" ::: "memory");  // t0 landed (own loads)
  __builtin_amdgcn_s_barrier();                     // all waves' t0 landed
  LDRD(afA, bfA, 0, 0, 0);                          // ph(0,0) operands

  for (int t = 0; t < NT; ++t) {
    const int buf = t & 1, nbuf = buf ^ 1;
    // ---- phase 0: MFMA ph(0,0) on set A; read ph(0,1) -> set B ----
    if (t < NT - 1) stg(g2, 0, 1, nbuf);  // A-kh1 for t+1
    LDRD(afB, bfB, buf, 0, 1);
    LGKM8;
    MMA(afA, bfA, 0);
    __builtin_amdgcn_s_barrier();
    // ---- phase 1: MFMA ph(0,1) on B; read ph(1,0) -> A ----
    if (t < NT - 2) stg(g1, 1, 0, buf);   // B-kh0 for t+2
    LDRD(afA, bfA, buf, 1, 0);
    LGKM8;
    MMA(afB, bfB, 1);
    __builtin_amdgcn_s_barrier();
    // ---- phase 2: MFMA ph(1,0) on A; read ph(1,1) -> B ----
    if (t < NT - 2) stg(g0, 0, 0, buf);   // A-kh0 for t+2
    LDRD(afB, bfB, buf, 1, 1);
    LGKM8;
    MMA(afA, bfA, 0);
    __builtin_amdgcn_s_barrier();
    // ---- phase 3: MFMA ph(1,1) on B; gate + read next tile ph(0,0) -> A ----
    if (t < NT - 2) {
      stg(g3, 1, 1, buf);                 // B-kh1 for t+2
      asm volatile("s_waitcnt vmcnt(6)" ::: "memory");
    } else if (t == NT - 2) {
      asm volatile("s_waitcnt vmcnt(0)" ::: "memory");
    }
    __builtin_amdgcn_s_barrier();         // all waves' t+1 loads landed
    if (t < NT - 1) {
      LDRD(afA, bfA, nbuf, 0, 0);
      LGKM8;
    } else {
      LGKM0;
    }
    MMA(afB, bfB, 1);
    __builtin_amdgcn_s_barrier();
  }

  // C/D layout (m74/m101): col = lane&31, row = (j&3) + 8*(j>>2) + 4*(lane>>5)
  float* Cp = C + (rowA0 + wm * 128) * (size_t)SIZE + rowB0 + wn * 64;
#pragma unroll
  for (int mb = 0; mb < 4; ++mb)
#pragma unroll
    for (int nb = 0; nb < 2; ++nb)
#pragma unroll
      for (int j = 0; j < 16; ++j)
        Cp[(size_t)(mb * 32 + (j & 3) + 8 * (j >> 2) + 4 * khi) * SIZE +
           nb * 32 + r32] = acc[mb][nb][j];
#undef LDRD
#undef MMA
#undef LGKM8
#undef LGKM0
}

// ---------------------------------------------------------------------------
extern "C" void kernel_launch(void* const* d_in, const int* in_sizes, int n_in,
                              void* d_out, int out_size, void* d_ws, size_t ws_size,
                              hipStream_t stream) {
  const float* p = (const float*)d_in[0];
  float* C = (float*)d_out;
  __bf16* Lb = (__bf16*)d_ws;  // 32 MB scratch

  build_L<<<SIZE, 256, 0, stream>>>(p, Lb);
  syrk8<<<NBG * NBG, 512, 0, stream>>>(Lb, C);
}

// Round 9
// 132.579 us; speedup vs baseline: 1.0168x; 1.0168x over previous
//
#include <hip/hip_runtime.h>
#include <hip/hip_bf16.h>

#define SIZE 4096
#define BM 256
#define BK 64
#define NT (SIZE / BK)     // 64 K-tiles
#define NBG (SIZE / BM)    // 16x16 grid of 256^2 tiles

typedef __bf16 bf16x8 __attribute__((ext_vector_type(8)));
typedef __bf16 bf16x4 __attribute__((ext_vector_type(4)));
typedef float f32x4 __attribute__((ext_vector_type(4)));
typedef float f32x16 __attribute__((ext_vector_type(16)));

__device__ __forceinline__ void gload_lds16(const void* gsrc, void* ldst) {
  __builtin_amdgcn_global_load_lds(
      (const __attribute__((address_space(1))) unsigned int*)gsrc,
      (__attribute__((address_space(3))) unsigned int*)ldst, 16, 0, 0);
}

// ---------------------------------------------------------------------------
// Kernel 1: build L (bf16). One 256-thread block per row. 4 cols/thread.
// fp32 throughout (matches reference underflow).
// ---------------------------------------------------------------------------
__global__ __launch_bounds__(256) void build_L(const float* __restrict__ p,
                                               __bf16* __restrict__ Lb) {
  const int row = blockIdx.x;
  const int tid = threadIdx.x;
  const int lane = tid & 63;
  const int wid = tid >> 6;
  const long base = (long)row * (row - 1) / 2;

  __shared__ float wtot[4];
  float carry = 1.0f;

  for (int j0 = 0; j0 < SIZE; j0 += 1024) {
    const int jb = j0 + tid * 4;
    if (j0 > row) {
      bf16x4 z = {(__bf16)0.0f, (__bf16)0.0f, (__bf16)0.0f, (__bf16)0.0f};
      *(bf16x4*)&Lb[(size_t)row * SIZE + jb] = z;
      continue;
    }
    float t[4], v[4];
#pragma unroll
    for (int e = 0; e < 4; ++e) {
      const int j = jb + e;
      if (j < row) {
        const float th = tanhf(p[base + j]);
        t[e] = th;
        v[e] = 1.0f - th * th;
      } else {
        t[e] = (j == row) ? 1.0f : 0.0f;
        v[e] = 1.0f;
      }
    }
    const float vt = v[0] * v[1] * v[2] * v[3];
    float incl = vt;
#pragma unroll
    for (int off = 1; off < 64; off <<= 1) {
      float o = __shfl_up(incl, off, 64);
      if (lane >= off) incl *= o;
    }
    if (lane == 63) wtot[wid] = incl;
    __syncthreads();
    float pre = carry;
    for (int w = 0; w < wid; ++w) pre *= wtot[w];
    float excl = __shfl_up(incl, 1, 64);
    if (lane == 0) excl = 1.0f;
    float s = pre * excl;
    bf16x4 out;
#pragma unroll
    for (int e = 0; e < 4; ++e) {
      out[e] = (__bf16)(t[e] * sqrtf(s));
      s *= v[e];
    }
    *(bf16x4*)&Lb[(size_t)row * SIZE + jb] = out;
    const float tot = wtot[0] * wtot[1] * wtot[2] * wtot[3];
    __syncthreads();
    carry *= tot;
  }
}

// ---------------------------------------------------------------------------
// Kernel 2: C = L*L^T, 256x256, BK=64, 8 waves, 32x32x16 MFMA, chunk-XOR
// swizzle (0 conflicts, R7/R8-verified). vs R8: MINIMAL LDS reads (24
// b128/wave/tile: B per kh read ONCE, register-resident across both mh
// phases) + cross-phase pipelining with exact counted lgkm waits.
// Phase i: {stage; reads(i+1) [4 or 8]; lgkm(N_issued) -> confirms ALL
//           prior phases' reads; MFMA(i); barrier}.
// Read/overwrite ledger (all barrier-proven):
//   ph1 stg buf B-kh0 : last read prev-t ph3 (bfA), confirmed ph0 lgkm(4)
//                       + ph0 barrier.
//   ph2 stg buf A-kh0 : last read prev-t ph3 (afA), same confirmation.
//   ph3 stg buf B-kh1 : last read ph1 (bfB), confirmed ph2 lgkm(4) + barrier.
//   ph0 stg nbuf A-kh1: last read prev-t ph1/ph2 (afA/afB kh1), confirmed
//                       prev-t ph3 lgkm(8) + final barrier.
// nbuf reads only in ph3, after vmcnt gate + barrier (R8-identical ledger:
// gate confirms through the t+1 A-kh1 stage exactly).
// ---------------------------------------------------------------------------
__global__ __launch_bounds__(512, 1) void syrk8(const __bf16* __restrict__ Lb,
                                                float* __restrict__ C) {
  __shared__ __bf16 lds[2][2][2][256][32];  // [buf][ab][kh][row][k] 128 KiB

  const int bid0 = blockIdx.x;
  const int bid = (bid0 & 7) * 32 + (bid0 >> 3);  // bijective XCD chunking
  const int bi = bid >> 4, bj = bid & 15;

  const int tid = threadIdx.x;
  const int lane = tid & 63;
  const int wid = tid >> 6;
  const int wm = wid >> 2;
  const int wn = wid & 3;
  const int r32 = lane & 31;
  const int khi = lane >> 5;
  const int swzf = ((r32 >> 1) & 3) ^ ((lane >> 4) & 1);
  const int ck0 = ((0 | khi) ^ swzf) * 8;
  const int ck1 = ((2 | khi) ^ swzf) * 8;

  const size_t rowA0 = (size_t)bi * 256;
  const size_t rowB0 = (size_t)bj * 256;

  const int srow = wid * 32 + (lane >> 2);
  const int sch = (lane & 3) ^ ((lane >> 3) & 3);
  const int soff0 = sch * 8;
  const int soff1 = (sch ^ 1) * 8;

  const __bf16* g0 = Lb + (rowA0 + srow) * SIZE;       // A kh0 stream
  const __bf16* g1 = Lb + (rowB0 + srow) * SIZE;       // B kh0
  const __bf16* g2 = Lb + (rowA0 + srow) * SIZE + 32;  // A kh1
  const __bf16* g3 = Lb + (rowB0 + srow) * SIZE + 32;  // B kh1

  auto stg = [&](const __bf16*& gp, int ab, int kh, int dstbuf) {
    __bf16* base = &lds[dstbuf][ab][kh][0][0];
    gload_lds16(gp + soff0, base + (wid * 32) * 32);
    gload_lds16(gp + (size_t)16 * SIZE + soff1, base + (wid * 32 + 16) * 32);
    gp += BK;
  };

  f32x16 acc[4][2] = {};
  bf16x8 afA[2][2], afB[2][2], bfA[2][2], bfB[2][2];  // [block][ks]

// 4 ds_read_b128: A m-half (MH) fragments for half-K KH
#define LDA(AF, BSEL, KH, MH)                                              \
  {                                                                        \
    _Pragma("unroll") for (int mb = 0; mb < 2; ++mb) {                     \
      const __bf16* ap =                                                   \
          &lds[BSEL][0][KH][wm * 128 + ((MH)*2 + mb) * 32 + r32][0];       \
      AF[mb][0] = *(const bf16x8*)(ap + ck0);                              \
      AF[mb][1] = *(const bf16x8*)(ap + ck1);                              \
    }                                                                      \
  }
// 4 ds_read_b128: full B set for half-K KH (reused across both mh phases)
#define LDB(BF, BSEL, KH)                                                  \
  {                                                                        \
    _Pragma("unroll") for (int nb = 0; nb < 2; ++nb) {                     \
      const __bf16* bp = &lds[BSEL][1][KH][wn * 64 + nb * 32 + r32][0];    \
      BF[nb][0] = *(const bf16x8*)(bp + ck0);                              \
      BF[nb][1] = *(const bf16x8*)(bp + ck1);                              \
    }                                                                      \
  }

#define MMA(AF, BF, MH)                                                    \
  {                                                                        \
    __builtin_amdgcn_s_setprio(1);                                         \
    _Pragma("unroll") for (int mb = 0; mb < 2; ++mb)                       \
        _Pragma("unroll") for (int nb = 0; nb < 2; ++nb)                   \
            _Pragma("unroll") for (int ks = 0; ks < 2; ++ks)               \
                acc[(MH)*2 + mb][nb] =                                     \
        __builtin_amdgcn_mfma_f32_32x32x16_bf16(AF[mb][ks], BF[nb][ks],    \
                                                acc[(MH)*2 + mb][nb], 0,   \
                                                0, 0);                     \
    __builtin_amdgcn_s_setprio(0);                                         \
  }

#define LGKM(N)                                                            \
  asm volatile("s_waitcnt lgkmcnt(" #N ")" ::: "memory");                  \
  __builtin_amdgcn_sched_barrier(0)

  // prologue: t0 all 4 halves (buf0), then t1's {B-kh0, A-kh0, B-kh1} (buf1)
  stg(g0, 0, 0, 0); stg(g1, 1, 0, 0); stg(g2, 0, 1, 0); stg(g3, 1, 1, 0);
  stg(g1, 1, 0, 1); stg(g0, 0, 0, 1); stg(g3, 1, 1, 1);
  asm volatile("s_waitcnt vmcnt(6)" ::: "memory");  // t0's 8 loads landed
  __builtin_amdgcn_s_barrier();
  LDA(afA, 0, 0, 0);  // ph(0,0) operands: confirmed by first LGKM(4)
  LDB(bfA, 0, 0);

  for (int t = 0; t < NT; ++t) {
    const int buf = t & 1, nbuf = buf ^ 1;
    // ---- ph0: MFMA(afA x bfA -> mh0); read afB <- (buf, kh0, mh1) ----
    if (t < NT - 1) stg(g2, 0, 1, nbuf);  // A-kh1 for t+1
    LDA(afB, buf, 0, 1);
    LGKM(4);
    MMA(afA, bfA, 0);
    __builtin_amdgcn_s_barrier();
    // ---- ph1: MFMA(afB x bfA -> mh1); read afA <- (buf,kh1,mh0), bfB ----
    if (t < NT - 2) stg(g1, 1, 0, buf);   // B-kh0 for t+2
    LDA(afA, buf, 1, 0);
    LDB(bfB, buf, 1);
    LGKM(8);
    MMA(afB, bfA, 1);
    __builtin_amdgcn_s_barrier();
    // ---- ph2: MFMA(afA x bfB -> mh0); read afB <- (buf, kh1, mh1) ----
    if (t < NT - 2) stg(g0, 0, 0, buf);   // A-kh0 for t+2
    LDA(afB, buf, 1, 1);
    LGKM(4);
    MMA(afA, bfB, 0);
    __builtin_amdgcn_s_barrier();
    // ---- ph3: gate; MFMA(afB x bfB -> mh1); read next tile kh0 sets ----
    if (t < NT - 2) {
      stg(g3, 1, 1, buf);                 // B-kh1 for t+2
      asm volatile("s_waitcnt vmcnt(6)" ::: "memory");
    } else if (t == NT - 2) {
      asm volatile("s_waitcnt vmcnt(0)" ::: "memory");
    }
    __builtin_amdgcn_s_barrier();         // all waves' t+1 loads landed
    if (t < NT - 1) {
      LDA(afA, nbuf, 0, 0);
      LDB(bfA, nbuf, 0);
      LGKM(8);
    } else {
      LGKM(0);
    }
    MMA(afB, bfB, 1);
    __builtin_amdgcn_s_barrier();
  }

  // C/D layout (m74/m101): col = lane&31, row = (j&3) + 8*(j>>2) + 4*(lane>>5)
  float* Cp = C + (rowA0 + wm * 128) * (size_t)SIZE + rowB0 + wn * 64;
#pragma unroll
  for (int mb = 0; mb < 4; ++mb)
#pragma unroll
    for (int nb = 0; nb < 2; ++nb)
#pragma unroll
      for (int j = 0; j < 16; ++j)
        Cp[(size_t)(mb * 32 + (j & 3) + 8 * (j >> 2) + 4 * khi) * SIZE +
           nb * 32 + r32] = acc[mb][nb][j];
#undef LDA
#undef LDB
#undef MMA
#undef LGKM
}

// ---------------------------------------------------------------------------
extern "C" void kernel_launch(void* const* d_in, const int* in_sizes, int n_in,
                              void* d_out, int out_size, void* d_ws, size_t ws_size,
                              hipStream_t stream) {
  const float* p = (const float*)d_in[0];
  float* C = (float*)d_out;
  __bf16* Lb = (__bf16*)d_ws;  // 32 MB scratch

  build_L<<<SIZE, 256, 0, stream>>>(p, Lb);
  syrk8<<<NBG * NBG, 512, 0, stream>>>(Lb, C);
}